// Round 1
// baseline (81.035 us; speedup 1.0000x reference)
//
#include <hip/hip_runtime.h>

#define BATCH 4096
#define DIM   128
#define TILE  256
#define NT    16   // 4096 / 256 tiles per dimension
// TEMP = 0.25 -> 1/T = 4; 4*log2(e):
#define EXP_SCALE 5.770780163555854f

typedef __bf16 bf16_t;
typedef __bf16 bf16x4 __attribute__((ext_vector_type(4)));
typedef __bf16 bf16x8 __attribute__((ext_vector_type(8)));
typedef float  f32x4  __attribute__((ext_vector_type(4)));

// ---------------------------------------------------------------------------
// Fused kernel: one block per 256x256 tile of S = Zi * Zj^T (grid 16x16 =
// 256 blocks = one per CU, single scheduling round).
//
// Phase 1: each block loads its fp32 input panels (emb_i rows ti*256..,
//   emb_j rows tj*256..), L2-normalizes in fp32 (32 lanes per row, shfl
//   reduce), and writes bf16 directly into LDS. Diagonal blocks (ti==tj)
//   also emit pos[k] = cos-sim in fp32. Inputs are 4 MB total -> fully
//   L2-resident; the 16x panel re-read costs ~2 us of L2 BW and removes
//   the separate normalize kernel + zi/zj global round-trip.
// Phase 2: bf16 MFMA 16x16x32, K=128 in 4 steps. 8 waves in a 2x4 grid,
//   each wave owns a 128x64 sub-tile: acc[8][4] f32x4, 128 MFMA/wave,
//   12 ds_read_b128 per 32 MFMA. LDS rows padded 128->136 elems (row
//   stride 272 B -> only free 2-way conflicts; 16B alignment preserved).
// Phase 3: e = exp2(EXP_SCALE * s); row partials reduce over l15 (shfl)
//   then over the 4 wc-waves (LDS); col partials reduce over quad (shfl)
//   then over the 2 wr-waves (LDS). Partial sums go to deterministic
//   global arrays rowP[tj][4096], colP[ti][4096] -- NO atomics, no
//   pre-zeroing dispatch, no cross-XCD contention.
// ---------------------------------------------------------------------------
__global__ __launch_bounds__(512, 2) void fused_kernel(
    const float* __restrict__ emb_i, const float* __restrict__ emb_j,
    float* __restrict__ rowP,   // [NT][BATCH], indexed [tj][global row]
    float* __restrict__ colP,   // [NT][BATCH], indexed [ti][global col]
    float* __restrict__ pos, float* __restrict__ out)
{
    __shared__ __align__(16) bf16_t zi_s[TILE][136];  // 68 KB
    __shared__ __align__(16) bf16_t zj_s[TILE][136];  // 68 KB
    __shared__ float rowRed[4][TILE];                 // 4 KB
    __shared__ float colRed[2][TILE];                 // 2 KB

    const int tid = threadIdx.x;
    const int ti = blockIdx.x, tj = blockIdx.y;

    // out accumulator for the finalize kernel; re-zeroed every launch.
    if ((ti | tj) == 0 && tid == 0) out[0] = 0.0f;

    // ---- Phase 1: normalize fp32 panels into bf16 LDS tiles ----
    {
        const int g  = tid >> 5;   // 16 groups of
        const int gl = tid & 31;   // 32 lanes; one full 512B row per group
        const float* bi = emb_i + (size_t)ti * TILE * DIM;
        const float* bj = emb_j + (size_t)tj * TILE * DIM;
#pragma unroll
        for (int it = 0; it < 16; ++it) {
            const int r = it * 16 + g;
            float4 a = *(const float4*)(bi + r * DIM + gl * 4);
            float4 b = *(const float4*)(bj + r * DIM + gl * 4);
            float sii = a.x * a.x + a.y * a.y + a.z * a.z + a.w * a.w;
            float sjj = b.x * b.x + b.y * b.y + b.z * b.z + b.w * b.w;
            float sij = a.x * b.x + a.y * b.y + a.z * b.z + a.w * b.w;
#pragma unroll
            for (int m = 1; m < 32; m <<= 1) {
                sii += __shfl_xor(sii, m);
                sjj += __shfl_xor(sjj, m);
                sij += __shfl_xor(sij, m);
            }
            const float inv_i = 1.0f / fmaxf(sqrtf(sii), 1e-12f);
            const float inv_j = 1.0f / fmaxf(sqrtf(sjj), 1e-12f);
            bf16x4 pi, pj;
            pi[0] = (bf16_t)(a.x * inv_i); pi[1] = (bf16_t)(a.y * inv_i);
            pi[2] = (bf16_t)(a.z * inv_i); pi[3] = (bf16_t)(a.w * inv_i);
            pj[0] = (bf16_t)(b.x * inv_j); pj[1] = (bf16_t)(b.y * inv_j);
            pj[2] = (bf16_t)(b.z * inv_j); pj[3] = (bf16_t)(b.w * inv_j);
            *(bf16x4*)&zi_s[r][gl * 4] = pi;
            *(bf16x4*)&zj_s[r][gl * 4] = pj;
            // positives: fp32 cos-sim, written once (by diagonal blocks only)
            if (ti == tj && gl == 0) pos[ti * TILE + r] = sij * inv_i * inv_j;
        }
    }
    __syncthreads();

    // ---- Phase 2: MFMA ----
    const int wave = tid >> 6;
    const int lane = tid & 63;
    const int l15  = lane & 15;
    const int quad = lane >> 4;
    const int wr   = wave >> 2;   // 0..1 : row half   (128 rows)
    const int wc   = wave & 3;    // 0..3 : col quarter (64 cols)

    f32x4 acc[8][4];
#pragma unroll
    for (int mr = 0; mr < 8; ++mr)
#pragma unroll
        for (int nc = 0; nc < 4; ++nc)
            acc[mr][nc] = (f32x4){0.f, 0.f, 0.f, 0.f};

#pragma unroll
    for (int ks = 0; ks < 4; ++ks) {
        const int k0 = ks * 32 + quad * 8;
        bf16x8 afrag[8], bfrag[4];
#pragma unroll
        for (int mr = 0; mr < 8; ++mr)
            afrag[mr] = *(const bf16x8*)&zi_s[wr * 128 + mr * 16 + l15][k0];
#pragma unroll
        for (int nc = 0; nc < 4; ++nc)
            bfrag[nc] = *(const bf16x8*)&zj_s[wc * 64 + nc * 16 + l15][k0];
#pragma unroll
        for (int mr = 0; mr < 8; ++mr)
#pragma unroll
            for (int nc = 0; nc < 4; ++nc)
                acc[mr][nc] = __builtin_amdgcn_mfma_f32_16x16x32_bf16(
                    afrag[mr], bfrag[nc], acc[mr][nc], 0, 0, 0);
    }

    // ---- Phase 3: exp + partial sums ----
    // C/D layout: col = l15, row = quad*4 + rr (within each 16x16 frag).
    float rowPart[8][4];
    float colPart[4] = {0.f, 0.f, 0.f, 0.f};
#pragma unroll
    for (int mr = 0; mr < 8; ++mr)
#pragma unroll
        for (int rr = 0; rr < 4; ++rr) rowPart[mr][rr] = 0.f;

#pragma unroll
    for (int mr = 0; mr < 8; ++mr)
#pragma unroll
        for (int nc = 0; nc < 4; ++nc)
#pragma unroll
            for (int rr = 0; rr < 4; ++rr) {
                const float e = exp2f(acc[mr][nc][rr] * EXP_SCALE);
                rowPart[mr][rr] += e;
                colPart[nc]     += e;
            }

    // Row sums: reduce over the 16 cols this lane-group covers.
#pragma unroll
    for (int mr = 0; mr < 8; ++mr)
#pragma unroll
        for (int rr = 0; rr < 4; ++rr) {
            float v = rowPart[mr][rr];
            v += __shfl_xor(v, 1);
            v += __shfl_xor(v, 2);
            v += __shfl_xor(v, 4);
            v += __shfl_xor(v, 8);
            if (l15 == 0)
                rowRed[wc][wr * 128 + mr * 16 + quad * 4 + rr] = v;
        }
    // Col sums: reduce over the 4 quads (rows within frag already summed).
#pragma unroll
    for (int nc = 0; nc < 4; ++nc) {
        float v = colPart[nc];
        v += __shfl_xor(v, 16);
        v += __shfl_xor(v, 32);
        if (quad == 0)
            colRed[wr][wc * 64 + nc * 16 + l15] = v;
    }
    __syncthreads();

    if (tid < TILE) {
        const float v = rowRed[0][tid] + rowRed[1][tid] +
                        rowRed[2][tid] + rowRed[3][tid];
        rowP[(size_t)tj * BATCH + ti * TILE + tid] = v;
    } else if (tid < 2 * TILE) {
        const int c = tid - TILE;
        colP[(size_t)ti * BATCH + tj * TILE + c] = colRed[0][c] + colRed[1][c];
    }
}

// ---------------------------------------------------------------------------
// Finalize: denom_k = sum of 16 tile partials; loss contribution
// log(rowDenom_k) + log(colDenom_k) - 8*pos_k.  16 blocks, each reduces
// 256 rows+cols and atomically adds its scaled partial into out[0]
// (out pre-zeroed by fused kernel block (0,0)).
// ---------------------------------------------------------------------------
__global__ __launch_bounds__(256) void finalize_kernel(
    const float* __restrict__ rowP, const float* __restrict__ colP,
    const float* __restrict__ pos, float* __restrict__ out)
{
    const int k = blockIdx.x * 256 + threadIdx.x;
    float rd = 0.f, cd = 0.f;
#pragma unroll
    for (int t = 0; t < NT; ++t) {
        rd += rowP[t * BATCH + k];
        cd += colP[t * BATCH + k];
    }
    float v = logf(rd) + logf(cd) - 8.0f * pos[k];
#pragma unroll
    for (int m = 1; m < 64; m <<= 1) v += __shfl_xor(v, m);
    __shared__ float red[4];
    if ((threadIdx.x & 63) == 0) red[threadIdx.x >> 6] = v;
    __syncthreads();
    if (threadIdx.x == 0)
        atomicAdd(out, (red[0] + red[1] + red[2] + red[3]) *
                           (1.0f / (2.0f * BATCH)));
}

extern "C" void kernel_launch(void* const* d_in, const int* in_sizes, int n_in,
                              void* d_out, int out_size, void* d_ws, size_t ws_size,
                              hipStream_t stream) {
    const float* emb_i = (const float*)d_in[0];
    const float* emb_j = (const float*)d_in[1];
    float* out = (float*)d_out;

    char* ws = (char*)d_ws;
    float* rowP = (float*)ws;                            // 256 KB
    float* colP = (float*)(ws + NT * BATCH * 4);         // 256 KB
    float* pos  = (float*)(ws + 2 * (NT * BATCH * 4));   // 16 KB

    fused_kernel<<<dim3(NT, NT), 512, 0, stream>>>(emb_i, emb_j, rowP, colP,
                                                   pos, out);
    finalize_kernel<<<BATCH / 256, 256, 0, stream>>>(rowP, colP, pos, out);
}